// Round 13
// baseline (227.426 us; speedup 1.0000x reference)
//
#include <hip/hip_runtime.h>
#include <hip/hip_bf16.h>
#include <cstdint>
#include <cstddef>

// ---------- problem constants ----------
static constexpr int Bn = 4, Tn = 2048, Cn = 1024, Hn = 16, HD = 64;
static constexpr int Mn = Bn * Tn;            // 8192 tokens
static constexpr float QSCALE = 0.03125f * 1.4426950408889634f;  // C^-0.5 * log2(e)

typedef __attribute__((ext_vector_type(8))) short s16x8;
typedef __attribute__((ext_vector_type(4))) short s16x4;
typedef __attribute__((ext_vector_type(4))) float f32x4;
typedef __attribute__((ext_vector_type(2))) unsigned u32x2;

#define DEVFN __device__ __forceinline__

DEVFN unsigned short f2bf(float f) {
  union { float f; unsigned u; } v; v.f = f;
  unsigned r = v.u + 0x7fffu + ((v.u >> 16) & 1u);   // RNE
  return (unsigned short)(r >> 16);
}

DEVFN float exp2_hw(float x) {                 // raw v_exp_f32: D = 2^S0 (|x| small)
  float r;
  asm("v_exp_f32 %0, %1" : "=v"(r) : "v"(x));
  return r;
}

// pack 2 fp32 -> 2 bf16 (round-half-up ~ RNE), result lo=bf16(a0), hi=bf16(a1)
DEVFN unsigned pack_bf16_rhu(float a0, float a1) {
  union { float f; unsigned u; } x0, x1;
  x0.f = a0; x1.f = a1;
  return __builtin_amdgcn_perm(x1.u + 0x8000u, x0.u + 0x8000u, 0x07060302u);
}

DEVFN void gload_lds16(const void* g, void* l) {
  __builtin_amdgcn_global_load_lds(
      (const __attribute__((address_space(1))) void*)g,
      (__attribute__((address_space(3))) void*)l, 16, 0, 0);
}

// ---------- prep: 4 weight cvt + mask bit-pack (activations now converted in-GEMM) ----------
__global__ __launch_bounds__(256) void k_prep(
    const float* __restrict__ wq, const float* __restrict__ wk,
    const float* __restrict__ wv, const float* __restrict__ wp,
    const int* __restrict__ mask,
    unsigned short* __restrict__ Wqb, unsigned short* __restrict__ Wkb,
    unsigned short* __restrict__ Wvb, unsigned short* __restrict__ Wpb,
    unsigned* __restrict__ bits) {
  const int NW = (Cn * Cn / 4) / 256;   // 1024 blocks per weight
  int bid = blockIdx.x, tid = threadIdx.x;
  if (bid < 4 * NW) {                   // weight cvt
    int t = bid / NW;
    const float* src = t == 0 ? wq : t == 1 ? wk : t == 2 ? wv : wp;
    unsigned short* dst = t == 0 ? Wqb : t == 1 ? Wkb : t == 2 ? Wvb : Wpb;
    int i = (bid & (NW - 1)) * 256 + tid;
    float4 vv = reinterpret_cast<const float4*>(src)[i];
    ushort4 o;
    o.x = f2bf(vv.x); o.y = f2bf(vv.y); o.z = f2bf(vv.z); o.w = f2bf(vv.w);
    reinterpret_cast<ushort4*>(dst)[i] = o;
  } else {                              // mask bit-pack
    int i = (bid - 4 * NW) * 256 + tid;
    unsigned long long b = __ballot(mask[i] != 0);
    int lane = tid & 63;
    if (lane == 0)        bits[i >> 5] = (unsigned)b;
    else if (lane == 32)  bits[i >> 5] = (unsigned)(b >> 32);
  }
}

// XCD-aware bijective swizzle for an (8,64) grid slice: 512 % 8 == 0
DEVFN void gemm_swz(int& bx, int& by) {
  int flat = blockIdx.y * 8 + blockIdx.x;
  int swz = (flat & 7) * 64 + (flat >> 3);
  bx = swz & 7; by = swz >> 3;
}

// ---------- QKV GEMM: A = fp32 (converted in staging), Bt = bf16 weights ----------
__global__ __launch_bounds__(256) void k_gemmQKV(
    const float* __restrict__ Aq, const float* __restrict__ Ak,
    const float* __restrict__ Av,
    const unsigned short* __restrict__ Wqb, const unsigned short* __restrict__ Wkb,
    const unsigned short* __restrict__ Wvb,
    unsigned short* __restrict__ Qb, unsigned short* __restrict__ Kb,
    unsigned short* __restrict__ Vb) {
  const int K = Cn, N = Cn;
  int z = blockIdx.z;
  const float* A           = z == 0 ? Aq : z == 1 ? Ak : Av;
  const unsigned short* Bt = z == 0 ? Wqb : z == 1 ? Wkb : Wvb;
  unsigned short* C        = z == 0 ? Qb : z == 1 ? Kb : Vb;
  float oscale             = z == 0 ? QSCALE : 1.0f;
  int bx, by; gemm_swz(bx, by);

  __shared__ __align__(16) char As[128 * 64 * 2];
  __shared__ __align__(16) char Bs[128 * 64 * 2];
  const int tid = threadIdx.x, lane = tid & 63, wid = tid >> 6;
  const int l15 = lane & 15, lg = lane >> 4;
  const int wm = (wid >> 1) * 64, wn = (wid & 1) * 64;
  const int m0 = by * 128, n0 = bx * 128;

  f32x4 acc[4][4];
#pragma unroll
  for (int i = 0; i < 4; ++i)
#pragma unroll
    for (int j = 0; j < 4; ++j) acc[i][j] = f32x4{0.f, 0.f, 0.f, 0.f};

  for (int k0 = 0; k0 < K; k0 += 64) {
    // B: bf16 weights via gload_lds (pre-swizzled source)
#pragma unroll
    for (int it = 0; it < 4; ++it) {
      int chunk = it * 256 + tid;
      int row = chunk >> 3;
      int kg = (chunk & 7) ^ (row & 7);
      gload_lds16(Bt + (size_t)(n0 + row) * K + k0 + kg * 8,
                  Bs + (it * 256 + wid * 64) * 16);
    }
    // A: fp32 reg-staged convert -> swizzled ds_write_b128 (conflict-free Latin square)
    f32x4 av[4][2];
#pragma unroll
    for (int it = 0; it < 4; ++it) {
      int chunk = it * 256 + tid;
      int row = chunk >> 3;
      int kgc = chunk & 7;
      const float* src = A + (size_t)(m0 + row) * K + k0 + kgc * 8;
      av[it][0] = *(const f32x4*)(src);
      av[it][1] = *(const f32x4*)(src + 4);
    }
#pragma unroll
    for (int it = 0; it < 4; ++it) {
      int chunk = it * 256 + tid;
      int row = chunk >> 3;
      int kgc = chunk & 7;
      union { unsigned u[4]; s16x8 v; } pk;
#pragma unroll
      for (int h = 0; h < 2; ++h) {
        pk.u[h * 2 + 0] = pack_bf16_rhu(av[it][h][0], av[it][h][1]);
        pk.u[h * 2 + 1] = pack_bf16_rhu(av[it][h][2], av[it][h][3]);
      }
      *(s16x8*)(As + row * 128 + ((kgc * 16) ^ ((row & 7) << 4))) = pk.v;
    }
    __syncthreads();
#pragma unroll
    for (int kk = 0; kk < 64; kk += 32) {
      s16x8 a[4], b[4];
#pragma unroll
      for (int i = 0; i < 4; ++i) {
        int ra = wm + i * 16 + l15;
        a[i] = *(const s16x8*)(As + ra * 128 + (((kk + lg * 8) * 2) ^ ((ra & 7) << 4)));
        int rb = wn + i * 16 + l15;
        b[i] = *(const s16x8*)(Bs + rb * 128 + (((kk + lg * 8) * 2) ^ ((rb & 7) << 4)));
      }
#pragma unroll
      for (int i = 0; i < 4; ++i)
#pragma unroll
        for (int j = 0; j < 4; ++j)
          acc[i][j] = __builtin_amdgcn_mfma_f32_16x16x32_bf16(a[i], b[j], acc[i][j], 0, 0, 0);
    }
    __syncthreads();
  }
#pragma unroll
  for (int i = 0; i < 4; ++i)
#pragma unroll
    for (int j = 0; j < 4; ++j)
#pragma unroll
      for (int q = 0; q < 4; ++q) {
        int r = m0 + wm + i * 16 + lg * 4 + q;   // C/D: col=lane&15, row=(lane>>4)*4+reg
        int c = n0 + wn + j * 16 + l15;
        ((unsigned short*)C)[(size_t)r * N + c] = f2bf(acc[i][j][q] * oscale);
      }
}

// ---------- O-projection GEMM: A = bf16 AO via gload_lds, fp32 out + bias ----------
__global__ __launch_bounds__(256) void k_gemmO(const unsigned short* __restrict__ A,
                                               const unsigned short* __restrict__ Bt,
                                               float* __restrict__ Cv,
                                               const float* __restrict__ bias) {
  const int K = Cn, N = Cn;
  int bx, by; gemm_swz(bx, by);
  __shared__ __align__(16) char As[128 * 64 * 2];
  __shared__ __align__(16) char Bs[128 * 64 * 2];
  const int tid = threadIdx.x, lane = tid & 63, wid = tid >> 6;
  const int l15 = lane & 15, lg = lane >> 4;
  const int wm = (wid >> 1) * 64, wn = (wid & 1) * 64;
  const int m0 = by * 128, n0 = bx * 128;

  f32x4 acc[4][4];
#pragma unroll
  for (int i = 0; i < 4; ++i)
#pragma unroll
    for (int j = 0; j < 4; ++j) acc[i][j] = f32x4{0.f, 0.f, 0.f, 0.f};

  for (int k0 = 0; k0 < K; k0 += 64) {
#pragma unroll
    for (int it = 0; it < 4; ++it) {
      int chunk = it * 256 + tid;
      int row = chunk >> 3;
      int kg = (chunk & 7) ^ (row & 7);
      gload_lds16(A + (size_t)(m0 + row) * K + k0 + kg * 8,
                  As + (it * 256 + wid * 64) * 16);
      gload_lds16(Bt + (size_t)(n0 + row) * K + k0 + kg * 8,
                  Bs + (it * 256 + wid * 64) * 16);
    }
    __syncthreads();
#pragma unroll
    for (int kk = 0; kk < 64; kk += 32) {
      s16x8 a[4], b[4];
#pragma unroll
      for (int i = 0; i < 4; ++i) {
        int ra = wm + i * 16 + l15;
        a[i] = *(const s16x8*)(As + ra * 128 + (((kk + lg * 8) * 2) ^ ((ra & 7) << 4)));
        int rb = wn + i * 16 + l15;
        b[i] = *(const s16x8*)(Bs + rb * 128 + (((kk + lg * 8) * 2) ^ ((rb & 7) << 4)));
      }
#pragma unroll
      for (int i = 0; i < 4; ++i)
#pragma unroll
        for (int j = 0; j < 4; ++j)
          acc[i][j] = __builtin_amdgcn_mfma_f32_16x16x32_bf16(a[i], b[j], acc[i][j], 0, 0, 0);
    }
    __syncthreads();
  }
#pragma unroll
  for (int i = 0; i < 4; ++i)
#pragma unroll
    for (int j = 0; j < 4; ++j)
#pragma unroll
      for (int q = 0; q < 4; ++q) {
        int r = m0 + wm + i * 16 + lg * 4 + q;
        int c = n0 + wn + j * 16 + l15;
        Cv[(size_t)r * N + c] = acc[i][j][q] + bias[c];
      }
}

// ---------- fused attention v11: v10 + denominator via ones-MFMA row-sum ----------
__global__ __launch_bounds__(256) void k_attn(const unsigned short* __restrict__ Qg,
                                              const unsigned short* __restrict__ Kg,
                                              const unsigned short* __restrict__ Vg,
                                              const unsigned* __restrict__ mbits,
                                              unsigned short* __restrict__ Og) {
  __shared__ __align__(16) char QPs[128 * 128];   // Q staging, then per-wave P tiles
  __shared__ __align__(16) char Ks[64 * 128];     // 64 k-rows x 64 d, swizzled (row&7)<<4
  __shared__ __align__(16) char Vts[64 * 128];    // V^T: row=d, col=k, swizzled ((d>>1)&7)<<4
  __shared__ unsigned Mw[128 * 2];                // mask words for current (qtile,ktile)

  const int tid = threadIdx.x, lane = tid & 63, wid = tid >> 6;
  const int l15 = lane & 15, lg = lane >> 4;
  const int qt = blockIdx.x, bh = blockIdx.y;
  const int b = bh >> 4, h = bh & 15;
  const size_t rowbase = (size_t)b * Tn;
  const int cbase = h * 64;

  const int dp = lane & 31;               // V: d-pair index, d0 = 2*dp
  const int g  = wid * 2 + (lane >> 5);   // V: k-group; k = g*8 + j
  const int qrm = tid >> 1, wmi = tid & 1;// mask: row / word

  // ---- prologue: issue ALL tile-0 loads, then barrier, then finish staging ----
#pragma unroll
  for (int it = 0; it < 4; ++it) {
    int chunk = it * 256 + tid;
    int row = chunk >> 3;
    int kg = (chunk & 7) ^ (row & 7);
    gload_lds16(Qg + (rowbase + qt * 128 + row) * Cn + cbase + kg * 8,
                QPs + (it * 256 + wid * 64) * 16);
  }
#pragma unroll
  for (int it = 0; it < 2; ++it) {
    int chunk = it * 256 + tid;
    int row = chunk >> 3;
    int kg = (chunk & 7) ^ (row & 7);
    gload_lds16(Kg + (rowbase + row) * Cn + cbase + kg * 8,
                Ks + (it * 256 + wid * 64) * 16);
  }
  unsigned w[8];
  {
    const unsigned* vsrc = (const unsigned*)(Vg + (rowbase + g * 8) * Cn + cbase) + dp;
#pragma unroll
    for (int j = 0; j < 8; ++j) w[j] = vsrc[(size_t)j * (Cn / 2)];
  }
  unsigned mreg = mbits[(size_t)(qt * 128 + qrm) * (Tn / 32) + wmi];
  __syncthreads();

  // lift Q to registers
  s16x8 qf[2][2];
#pragma unroll
  for (int m = 0; m < 2; ++m)
#pragma unroll
    for (int kh = 0; kh < 2; ++kh) {
      int ra = wid * 32 + m * 16 + l15;
      qf[m][kh] = *(const s16x8*)(QPs + ra * 128 + ((kh * 64 + lg * 16) ^ ((ra & 7) << 4)));
    }
  // finish tile-0 staging: V perm -> Vts, mask -> Mw
  {
    union { unsigned u[4]; s16x8 v; } lo, hi;
#pragma unroll
    for (int j = 0; j < 4; ++j) {
      lo.u[j] = __builtin_amdgcn_perm(w[2 * j + 1], w[2 * j], 0x05040100u);
      hi.u[j] = __builtin_amdgcn_perm(w[2 * j + 1], w[2 * j], 0x07060302u);
    }
    int d0 = dp * 2, swv = (dp & 7) << 4;
    *(s16x8*)(Vts + d0 * 128 + ((g * 16) ^ swv)) = lo.v;
    *(s16x8*)(Vts + (d0 + 1) * 128 + ((g * 16) ^ swv)) = hi.v;
    Mw[qrm * 2 + wmi] = mreg;
  }

  f32x4 oacc[2][4];                       // O row = m*16+lg*4+reg, col = n*16+l15
#pragma unroll
  for (int m = 0; m < 2; ++m)
#pragma unroll
    for (int n = 0; n < 4; ++n) oacc[m][n] = f32x4{0.f, 0.f, 0.f, 0.f};
  f32x4 lacc[2];                          // denominator row-sums (same row layout)
  lacc[0] = f32x4{0.f, 0.f, 0.f, 0.f};
  lacc[1] = f32x4{0.f, 0.f, 0.f, 0.f};
  s16x8 vones;                            // bf16 1.0 x8
#pragma unroll
  for (int e = 0; e < 8; ++e) vones[e] = (short)0x3F80;

  char* Pw = QPs + wid * (32 * 128);

  for (int kt = 0; kt < Tn / 64; ++kt) {
    // ---- S^T = K Q^T ----
    f32x4 sacc[4][2];
#pragma unroll
    for (int n = 0; n < 4; ++n)
#pragma unroll
      for (int m = 0; m < 2; ++m) sacc[n][m] = f32x4{0.f, 0.f, 0.f, 0.f};
#pragma unroll
    for (int kk = 0; kk < 64; kk += 32) {
      s16x8 kfr[4];
#pragma unroll
      for (int n = 0; n < 4; ++n) {
        int rb = n * 16 + l15;
        kfr[n] = *(const s16x8*)(Ks + rb * 128 + (((kk + lg * 8) * 2) ^ ((rb & 7) << 4)));
      }
#pragma unroll
      for (int n = 0; n < 4; ++n)
#pragma unroll
        for (int m = 0; m < 2; ++m)
          sacc[n][m] = __builtin_amdgcn_mfma_f32_16x16x32_bf16(kfr[n], qf[m][kk >> 5],
                                                               sacc[n][m], 0, 0, 0);
    }
    __syncthreads();   // barrier1: all QK^T reads of Ks done -> safe to restage Ks

    // ---- issue stage(t+1): K gload_lds, V->regs, mask->reg ----
    {
      int ktn = (kt + 1) & (Tn / 64 - 1);
#pragma unroll
      for (int it = 0; it < 2; ++it) {
        int chunk = it * 256 + tid;
        int row = chunk >> 3;
        int kg = (chunk & 7) ^ (row & 7);
        gload_lds16(Kg + (rowbase + ktn * 64 + row) * Cn + cbase + kg * 8,
                    Ks + (it * 256 + wid * 64) * 16);
      }
      const unsigned* vsrc =
          (const unsigned*)(Vg + (rowbase + ktn * 64 + g * 8) * Cn + cbase) + dp;
#pragma unroll
      for (int j = 0; j < 8; ++j) w[j] = vsrc[(size_t)j * (Cn / 2)];
      mreg = mbits[(size_t)(qt * 128 + qrm) * (Tn / 32) + ktn * 2 + wmi];
    }

    // ---- no-max softmax (masked logit -> 0 -> p=1), v_exp_f32, v_perm pack ----
#pragma unroll
    for (int qi = 0; qi < 2; ++qi) {
      int qr = wid * 32 + qi * 16 + l15;
      unsigned w0 = Mw[qr * 2], w1 = Mw[qr * 2 + 1];
      int qloc = qi * 16 + l15;
      unsigned swp = (unsigned)((qloc & 7) << 4);
#pragma unroll
      for (int kf = 0; kf < 4; ++kf) {
        unsigned wm_ = (kf < 2) ? w0 : w1;
        unsigned bits4 = wm_ >> ((kf & 1) * 16 + lg * 4);
        unsigned pb[4];
#pragma unroll
        for (int r = 0; r < 4; ++r) {
          int smear = (int)(bits4 << (31 - r)) >> 31;        // 0 or -1
          union { float f; unsigned u; } sv; sv.f = sacc[kf][qi][r];
          sv.u &= (unsigned)smear;                           // masked -> 0.0f
          union { float f; unsigned u; } pc; pc.f = exp2_hw(sv.f);
          pb[r] = pc.u;
        }
        union { u32x2 u; s16x4 s; } pk;
        pk.u.x = __builtin_amdgcn_perm(pb[1], pb[0], 0x07060302u);
        pk.u.y = __builtin_amdgcn_perm(pb[3], pb[2], 0x07060302u);
        *(s16x4*)(Pw + qloc * 128 + (((unsigned)(kf * 32 + lg * 8)) ^ swp)) = pk.s;
      }
    }
    asm volatile("" ::: "memory");   // forbid hoisting PV ds_reads above P ds_writes

    // ---- O += P V ; denominator += P . ones ----
#pragma unroll
    for (int kk = 0; kk < 64; kk += 32) {
      s16x8 pa[2], vb[4];
#pragma unroll
      for (int m = 0; m < 2; ++m) {
        int rp = m * 16 + l15;
        pa[m] = *(const s16x8*)(Pw + rp * 128 + (((kk + lg * 8) * 2) ^ ((rp & 7) << 4)));
      }
#pragma unroll
      for (int n = 0; n < 4; ++n) {
        int rv = n * 16 + l15;
        vb[n] = *(const s16x8*)(Vts + rv * 128 + (((kk + lg * 8) * 2) ^ (((rv >> 1) & 7) << 4)));
      }
#pragma unroll
      for (int m = 0; m < 2; ++m) {
#pragma unroll
        for (int n = 0; n < 4; ++n)
          oacc[m][n] = __builtin_amdgcn_mfma_f32_16x16x32_bf16(pa[m], vb[n], oacc[m][n], 0, 0, 0);
        lacc[m] = __builtin_amdgcn_mfma_f32_16x16x32_bf16(pa[m], vones, lacc[m], 0, 0, 0);
      }
    }
    __syncthreads();   // barrier2: all PV reads of Vts / softmax reads of Mw done

    // ---- finish stage(t+1): V perm -> Vts, mask -> Mw ----
    {
      union { unsigned u[4]; s16x8 v; } lo, hi;
#pragma unroll
      for (int j = 0; j < 4; ++j) {
        lo.u[j] = __builtin_amdgcn_perm(w[2 * j + 1], w[2 * j], 0x05040100u);
        hi.u[j] = __builtin_amdgcn_perm(w[2 * j + 1], w[2 * j], 0x07060302u);
      }
      int d0 = dp * 2, swv = (dp & 7) << 4;
      *(s16x8*)(Vts + d0 * 128 + ((g * 16) ^ swv)) = lo.v;
      *(s16x8*)(Vts + (d0 + 1) * 128 + ((g * 16) ^ swv)) = hi.v;
      Mw[qrm * 2 + wmi] = mreg;
    }
  }

  // ---- epilogue: divide by MFMA-computed denominator (already in-lane), write bf16 ----
#pragma unroll
  for (int m = 0; m < 2; ++m)
#pragma unroll
    for (int q = 0; q < 4; ++q) {
      float inv = 1.0f / lacc[m][q];
      int rg = qt * 128 + wid * 32 + m * 16 + lg * 4 + q;
#pragma unroll
      for (int n = 0; n < 4; ++n)
        Og[(rowbase + rg) * Cn + cbase + n * 16 + l15] = f2bf(oacc[m][n][q] * inv);
    }
}

// ---------- host ----------
extern "C" void kernel_launch(void* const* d_in, const int* in_sizes, int n_in,
                              void* d_out, int out_size, void* d_ws, size_t ws_size,
                              hipStream_t stream) {
  (void)in_sizes; (void)n_in; (void)out_size; (void)ws_size;
  const float* query = (const float*)d_in[0];
  const float* key_  = (const float*)d_in[1];
  const float* value = (const float*)d_in[2];
  const int*   mask  = (const int*)d_in[3];
  const float* Wq = (const float*)d_in[4];
  const float* Wk = (const float*)d_in[5];
  const float* Wv = (const float*)d_in[6];
  const float* Wp = (const float*)d_in[7];
  const float* bp = (const float*)d_in[8];

  char* ws = (char*)d_ws;
  const size_t SX = (size_t)Mn * Cn * 2;   // 16 MiB
  const size_t SW = (size_t)Cn * Cn * 2;   // 2 MiB
  unsigned short* AO  = (unsigned short*)(ws);              // attention output (bf16)
  unsigned short* Wqb = (unsigned short*)(ws + 3 * SX);
  unsigned short* Wkb = (unsigned short*)(ws + 3 * SX + SW);
  unsigned short* Wvb = (unsigned short*)(ws + 3 * SX + 2 * SW);
  unsigned short* Wpb = (unsigned short*)(ws + 3 * SX + 3 * SW);
  unsigned short* Qb  = (unsigned short*)(ws + 3 * SX + 4 * SW);
  unsigned short* Kb  = (unsigned short*)(ws + 4 * SX + 4 * SW);
  unsigned short* Vb  = (unsigned short*)(ws + 5 * SX + 4 * SW);
  unsigned*       mb  = (unsigned*)(ws + 6 * SX + 4 * SW);

  const int NPREP = 4 * ((Cn * Cn / 4) / 256) + (Tn * Tn) / 256;  // 4096 + 16384
  k_prep<<<dim3(NPREP), dim3(256), 0, stream>>>(Wq, Wk, Wv, Wp, mask,
                                                Wqb, Wkb, Wvb, Wpb, mb);

  k_gemmQKV<<<dim3(8, 64, 3), dim3(256), 0, stream>>>(query, key_, value,
                                                      Wqb, Wkb, Wvb, Qb, Kb, Vb);

  k_attn<<<dim3(16, 64), dim3(256), 0, stream>>>(Qb, Kb, Vb, mb, AO);

  k_gemmO<<<dim3(8, 64), dim3(256), 0, stream>>>(AO, Wpb, (float*)d_out, bp);
}

// Round 14
// 224.149 us; speedup vs baseline: 1.0146x; 1.0146x over previous
//
#include <hip/hip_runtime.h>
#include <hip/hip_bf16.h>
#include <cstdint>
#include <cstddef>

// ---------- problem constants ----------
static constexpr int Bn = 4, Tn = 2048, Cn = 1024, Hn = 16, HD = 64;
static constexpr int Mn = Bn * Tn;            // 8192 tokens
static constexpr float QSCALE = 0.03125f * 1.4426950408889634f;  // C^-0.5 * log2(e)

typedef __attribute__((ext_vector_type(8))) short s16x8;
typedef __attribute__((ext_vector_type(4))) short s16x4;
typedef __attribute__((ext_vector_type(4))) float f32x4;
typedef __attribute__((ext_vector_type(2))) unsigned u32x2;

#define DEVFN __device__ __forceinline__

DEVFN unsigned short f2bf(float f) {
  union { float f; unsigned u; } v; v.f = f;
  unsigned r = v.u + 0x7fffu + ((v.u >> 16) & 1u);   // RNE
  return (unsigned short)(r >> 16);
}

DEVFN float exp2_hw(float x) {                 // raw v_exp_f32: D = 2^S0 (|x| small)
  float r;
  asm("v_exp_f32 %0, %1" : "=v"(r) : "v"(x));
  return r;
}

DEVFN void gload_lds16(const void* g, void* l) {
  __builtin_amdgcn_global_load_lds(
      (const __attribute__((address_space(1))) void*)g,
      (__attribute__((address_space(3))) void*)l, 16, 0, 0);
}

// ---------- fused prep: 3 big cvt + 4 weight cvt + mask bit-pack, one launch ----------
__global__ __launch_bounds__(256) void k_prep(
    const float* __restrict__ q, const float* __restrict__ k, const float* __restrict__ v,
    const float* __restrict__ wq, const float* __restrict__ wk,
    const float* __restrict__ wv, const float* __restrict__ wp,
    const int* __restrict__ mask,
    unsigned short* __restrict__ Xq, unsigned short* __restrict__ Xk,
    unsigned short* __restrict__ Xv,
    unsigned short* __restrict__ Wqb, unsigned short* __restrict__ Wkb,
    unsigned short* __restrict__ Wvb, unsigned short* __restrict__ Wpb,
    unsigned* __restrict__ bits) {
  const int NX = (Mn * Cn / 4) / 256;   // 8192 blocks per activation tensor
  const int NW = (Cn * Cn / 4) / 256;   // 1024 blocks per weight
  int bid = blockIdx.x, tid = threadIdx.x;
  if (bid < 3 * NX) {                   // activation cvt
    const float* src = bid < NX ? q : (bid < 2 * NX ? k : v);
    unsigned short* dst = bid < NX ? Xq : (bid < 2 * NX ? Xk : Xv);
    int i = (bid & (NX - 1)) * 256 + tid;
    float4 vv = reinterpret_cast<const float4*>(src)[i];
    ushort4 o;
    o.x = f2bf(vv.x); o.y = f2bf(vv.y); o.z = f2bf(vv.z); o.w = f2bf(vv.w);
    reinterpret_cast<ushort4*>(dst)[i] = o;
  } else if (bid < 3 * NX + 4 * NW) {   // weight cvt
    int t = (bid - 3 * NX) / NW;
    const float* src = t == 0 ? wq : t == 1 ? wk : t == 2 ? wv : wp;
    unsigned short* dst = t == 0 ? Wqb : t == 1 ? Wkb : t == 2 ? Wvb : Wpb;
    int i = ((bid - 3 * NX) & (NW - 1)) * 256 + tid;
    float4 vv = reinterpret_cast<const float4*>(src)[i];
    ushort4 o;
    o.x = f2bf(vv.x); o.y = f2bf(vv.y); o.z = f2bf(vv.z); o.w = f2bf(vv.w);
    reinterpret_cast<ushort4*>(dst)[i] = o;
  } else {                              // mask bit-pack
    int i = (bid - 3 * NX - 4 * NW) * 256 + tid;
    unsigned long long b = __ballot(mask[i] != 0);
    int lane = tid & 63;
    if (lane == 0)        bits[i >> 5] = (unsigned)b;
    else if (lane == 32)  bits[i >> 5] = (unsigned)(b >> 32);
  }
}

// ---------- 128x128 GEMM body, C[m,n] = sum_k A[m,k]*Bt[n,k]  (both K-major bf16) ----------
template <bool F32OUT>
DEVFN void gemm_body(const unsigned short* __restrict__ A,
                     const unsigned short* __restrict__ Bt,
                     void* __restrict__ Cv, const float* __restrict__ bias,
                     float oscale, int bx, int by) {
  const int N = Cn, K = Cn;
  __shared__ __align__(16) char As[128 * 64 * 2];
  __shared__ __align__(16) char Bs[128 * 64 * 2];
  const int tid = threadIdx.x, lane = tid & 63, wid = tid >> 6;
  const int l15 = lane & 15, lg = lane >> 4;
  const int wm = (wid >> 1) * 64, wn = (wid & 1) * 64;
  const int m0 = by * 128, n0 = bx * 128;

  f32x4 acc[4][4];
#pragma unroll
  for (int i = 0; i < 4; ++i)
#pragma unroll
    for (int j = 0; j < 4; ++j) acc[i][j] = f32x4{0.f, 0.f, 0.f, 0.f};

  for (int k0 = 0; k0 < K; k0 += 64) {
#pragma unroll
    for (int it = 0; it < 4; ++it) {
      int chunk = it * 256 + tid;
      int row = chunk >> 3;
      int kg = (chunk & 7) ^ (row & 7);          // inverse-swizzled SOURCE (rule 21)
      gload_lds16(A + (size_t)(m0 + row) * K + k0 + kg * 8,
                  As + (it * 256 + wid * 64) * 16);
      gload_lds16(Bt + (size_t)(n0 + row) * K + k0 + kg * 8,
                  Bs + (it * 256 + wid * 64) * 16);
    }
    __syncthreads();
#pragma unroll
    for (int kk = 0; kk < 64; kk += 32) {
      s16x8 a[4], b[4];
#pragma unroll
      for (int i = 0; i < 4; ++i) {
        int ra = wm + i * 16 + l15;
        a[i] = *(const s16x8*)(As + ra * 128 + (((kk + lg * 8) * 2) ^ ((ra & 7) << 4)));
        int rb = wn + i * 16 + l15;
        b[i] = *(const s16x8*)(Bs + rb * 128 + (((kk + lg * 8) * 2) ^ ((rb & 7) << 4)));
      }
#pragma unroll
      for (int i = 0; i < 4; ++i)
#pragma unroll
        for (int j = 0; j < 4; ++j)
          acc[i][j] = __builtin_amdgcn_mfma_f32_16x16x32_bf16(a[i], b[j], acc[i][j], 0, 0, 0);
    }
    __syncthreads();
  }
#pragma unroll
  for (int i = 0; i < 4; ++i)
#pragma unroll
    for (int j = 0; j < 4; ++j)
#pragma unroll
      for (int q = 0; q < 4; ++q) {
        int r = m0 + wm + i * 16 + lg * 4 + q;   // C/D: col=lane&15, row=(lane>>4)*4+reg
        int c = n0 + wn + j * 16 + l15;
        float v = acc[i][j][q];
        if (F32OUT) ((float*)Cv)[(size_t)r * N + c] = v + bias[c];
        else        ((unsigned short*)Cv)[(size_t)r * N + c] = f2bf(v * oscale);
      }
}

// XCD-aware bijective swizzle for an (8,64) grid slice: 512 % 8 == 0
DEVFN void gemm_swz(int& bx, int& by) {
  int flat = blockIdx.y * 8 + blockIdx.x;
  int swz = (flat & 7) * 64 + (flat >> 3);
  bx = swz & 7; by = swz >> 3;
}

// ---------- batched QKV projection GEMM (grid.z selects tensor) ----------
__global__ __launch_bounds__(256) void k_gemmQKV(
    const unsigned short* __restrict__ Xq, const unsigned short* __restrict__ Xk,
    const unsigned short* __restrict__ Xv,
    const unsigned short* __restrict__ Wqb, const unsigned short* __restrict__ Wkb,
    const unsigned short* __restrict__ Wvb,
    unsigned short* __restrict__ Qb, unsigned short* __restrict__ Kb,
    unsigned short* __restrict__ Vb) {
  int z = blockIdx.z;
  const unsigned short* A  = z == 0 ? Xq : z == 1 ? Xk : Xv;
  const unsigned short* Bt = z == 0 ? Wqb : z == 1 ? Wkb : Wvb;
  unsigned short* C        = z == 0 ? Qb : z == 1 ? Kb : Vb;
  float oscale             = z == 0 ? QSCALE : 1.0f;
  int bx, by; gemm_swz(bx, by);
  gemm_body<false>(A, Bt, C, nullptr, oscale, bx, by);
}

// ---------- output projection GEMM (fp32 out + bias) ----------
__global__ __launch_bounds__(256) void k_gemmO(const unsigned short* __restrict__ A,
                                               const unsigned short* __restrict__ Bt,
                                               float* __restrict__ C,
                                               const float* __restrict__ bias) {
  int bx, by; gemm_swz(bx, by);
  gemm_body<true>(A, Bt, C, bias, 1.0f, bx, by);
}

// ---------- fused attention v10: raw v_exp_f32 softmax (R12-validated best) ----------
__global__ __launch_bounds__(256) void k_attn(const unsigned short* __restrict__ Qg,
                                              const unsigned short* __restrict__ Kg,
                                              const unsigned short* __restrict__ Vg,
                                              const unsigned* __restrict__ mbits,
                                              unsigned short* __restrict__ Og) {
  // LDS ~34 KB total -> 4 blocks/CU; grid is exactly 4 blocks/CU (no tail)
  __shared__ __align__(16) char QPs[128 * 128];   // Q staging, then per-wave P tiles
  __shared__ __align__(16) char Ks[64 * 128];     // 64 k-rows x 64 d, swizzled (row&7)<<4
  __shared__ __align__(16) char Vts[64 * 128];    // V^T: row=d, col=k, swizzled ((d>>1)&7)<<4
  __shared__ unsigned Mw[128 * 2];                // mask words for current (qtile,ktile)
  __shared__ float Ls[128];                       // softmax denominators (per block row)

  const int tid = threadIdx.x, lane = tid & 63, wid = tid >> 6;
  const int l15 = lane & 15, lg = lane >> 4;
  const int qt = blockIdx.x, bh = blockIdx.y;     // natural mapping (R9-validated perf)
  const int b = bh >> 4, h = bh & 15;
  const size_t rowbase = (size_t)b * Tn;
  const int cbase = h * 64;

  // per-thread staging roles (constant all iterations)
  const int dp = lane & 31;               // V: d-pair index, d0 = 2*dp
  const int g  = wid * 2 + (lane >> 5);   // V: k-group; k = g*8 + j
  const int qrm = tid >> 1, wmi = tid & 1;// mask: row / word

  // ---- prologue: issue ALL tile-0 loads, then barrier, then finish staging ----
#pragma unroll
  for (int it = 0; it < 4; ++it) {
    int chunk = it * 256 + tid;
    int row = chunk >> 3;
    int kg = (chunk & 7) ^ (row & 7);
    gload_lds16(Qg + (rowbase + qt * 128 + row) * Cn + cbase + kg * 8,
                QPs + (it * 256 + wid * 64) * 16);
  }
#pragma unroll
  for (int it = 0; it < 2; ++it) {
    int chunk = it * 256 + tid;
    int row = chunk >> 3;
    int kg = (chunk & 7) ^ (row & 7);
    gload_lds16(Kg + (rowbase + row) * Cn + cbase + kg * 8,
                Ks + (it * 256 + wid * 64) * 16);
  }
  unsigned w[8];
  {
    const unsigned* vsrc = (const unsigned*)(Vg + (rowbase + g * 8) * Cn + cbase) + dp;
#pragma unroll
    for (int j = 0; j < 8; ++j) w[j] = vsrc[(size_t)j * (Cn / 2)];
  }
  unsigned mreg = mbits[(size_t)(qt * 128 + qrm) * (Tn / 32) + wmi];
  __syncthreads();

  // lift Q to registers (wave reads only its own rows; QPs then becomes per-wave P)
  s16x8 qf[2][2];
#pragma unroll
  for (int m = 0; m < 2; ++m)
#pragma unroll
    for (int kh = 0; kh < 2; ++kh) {
      int ra = wid * 32 + m * 16 + l15;
      qf[m][kh] = *(const s16x8*)(QPs + ra * 128 + ((kh * 64 + lg * 16) ^ ((ra & 7) << 4)));
    }
  // finish tile-0 staging: V perm -> Vts, mask -> Mw
  {
    union { unsigned u[4]; s16x8 v; } lo, hi;
#pragma unroll
    for (int j = 0; j < 4; ++j) {
      lo.u[j] = __builtin_amdgcn_perm(w[2 * j + 1], w[2 * j], 0x05040100u);
      hi.u[j] = __builtin_amdgcn_perm(w[2 * j + 1], w[2 * j], 0x07060302u);
    }
    int d0 = dp * 2, swv = (dp & 7) << 4;
    *(s16x8*)(Vts + d0 * 128 + ((g * 16) ^ swv)) = lo.v;
    *(s16x8*)(Vts + (d0 + 1) * 128 + ((g * 16) ^ swv)) = hi.v;
    Mw[qrm * 2 + wmi] = mreg;
  }

  f32x4 oacc[2][4];                       // [m][n]; O row = m*16+lg*4+reg, col = n*16+l15
#pragma unroll
  for (int m = 0; m < 2; ++m)
#pragma unroll
    for (int n = 0; n < 4; ++n) oacc[m][n] = f32x4{0.f, 0.f, 0.f, 0.f};
  float lsum[2] = {0.0f, 0.0f};           // per-thread denominator partials (q = qf*16+l15)

  char* Pw = QPs + wid * (32 * 128);

  for (int kt = 0; kt < Tn / 64; ++kt) {
    // ---- S^T = K Q^T : sacc[kf][qf]; row=k_local=kf*16+lg*4+reg, col=q=qf*16+l15 ----
    f32x4 sacc[4][2];
#pragma unroll
    for (int n = 0; n < 4; ++n)
#pragma unroll
      for (int m = 0; m < 2; ++m) sacc[n][m] = f32x4{0.f, 0.f, 0.f, 0.f};
#pragma unroll
    for (int kk = 0; kk < 64; kk += 32) {
      s16x8 kfr[4];
#pragma unroll
      for (int n = 0; n < 4; ++n) {
        int rb = n * 16 + l15;
        kfr[n] = *(const s16x8*)(Ks + rb * 128 + (((kk + lg * 8) * 2) ^ ((rb & 7) << 4)));
      }
#pragma unroll
      for (int n = 0; n < 4; ++n)
#pragma unroll
        for (int m = 0; m < 2; ++m)
          sacc[n][m] = __builtin_amdgcn_mfma_f32_16x16x32_bf16(kfr[n], qf[m][kk >> 5],
                                                               sacc[n][m], 0, 0, 0);
    }
    __syncthreads();   // barrier1: all QK^T reads of Ks done -> safe to restage Ks

    // ---- issue stage(t+1): K gload_lds, V->regs, mask->reg (latency hidden below) ----
    {
      int ktn = (kt + 1) & (Tn / 64 - 1);
#pragma unroll
      for (int it = 0; it < 2; ++it) {
        int chunk = it * 256 + tid;
        int row = chunk >> 3;
        int kg = (chunk & 7) ^ (row & 7);
        gload_lds16(Kg + (rowbase + ktn * 64 + row) * Cn + cbase + kg * 8,
                    Ks + (it * 256 + wid * 64) * 16);
      }
      const unsigned* vsrc =
          (const unsigned*)(Vg + (rowbase + ktn * 64 + g * 8) * Cn + cbase) + dp;
#pragma unroll
      for (int j = 0; j < 8; ++j) w[j] = vsrc[(size_t)j * (Cn / 2)];
      mreg = mbits[(size_t)(qt * 128 + qrm) * (Tn / 32) + ktn * 2 + wmi];
    }

    // ---- no-max softmax on S^T (masked logit -> 0 -> p=1), v_exp_f32, v_perm pack ----
#pragma unroll
    for (int qi = 0; qi < 2; ++qi) {
      int qr = wid * 32 + qi * 16 + l15;     // block-local q row
      unsigned w0 = Mw[qr * 2], w1 = Mw[qr * 2 + 1];
      int qloc = qi * 16 + l15;              // wave-local P row
      unsigned swp = (unsigned)((qloc & 7) << 4);
      float psum = 0.0f;
#pragma unroll
      for (int kf = 0; kf < 4; ++kf) {
        unsigned wm_ = (kf < 2) ? w0 : w1;
        unsigned bits4 = wm_ >> ((kf & 1) * 16 + lg * 4);
        unsigned pb[4];
#pragma unroll
        for (int r = 0; r < 4; ++r) {
          int smear = (int)(bits4 << (31 - r)) >> 31;        // 0 or -1 (bfe)
          union { float f; unsigned u; } sv; sv.f = sacc[kf][qi][r];
          sv.u &= (unsigned)smear;                           // masked -> 0.0f
          float pv = exp2_hw(sv.f);                          // log2e pre-folded into Q
          psum += pv;
          union { float f; unsigned u; } pc; pc.f = pv; pb[r] = pc.u;
        }
        union { u32x2 u; s16x4 s; } pk;                      // truncate-pack 4 bf16
        pk.u.x = __builtin_amdgcn_perm(pb[1], pb[0], 0x07060302u);
        pk.u.y = __builtin_amdgcn_perm(pb[3], pb[2], 0x07060302u);
        *(s16x4*)(Pw + qloc * 128 + (((unsigned)(kf * 32 + lg * 8)) ^ swp)) = pk.s;
      }
      lsum[qi] += psum;
    }
    // keep compiler from hoisting PV ds_reads above P ds_writes
    asm volatile("" ::: "memory");

    // ---- O += P V ----
#pragma unroll
    for (int kk = 0; kk < 64; kk += 32) {
      s16x8 pa[2], vb[4];
#pragma unroll
      for (int m = 0; m < 2; ++m) {
        int rp = m * 16 + l15;
        pa[m] = *(const s16x8*)(Pw + rp * 128 + (((kk + lg * 8) * 2) ^ ((rp & 7) << 4)));
      }
#pragma unroll
      for (int n = 0; n < 4; ++n) {
        int rv = n * 16 + l15;
        vb[n] = *(const s16x8*)(Vts + rv * 128 + (((kk + lg * 8) * 2) ^ (((rv >> 1) & 7) << 4)));
      }
#pragma unroll
      for (int m = 0; m < 2; ++m)
#pragma unroll
        for (int n = 0; n < 4; ++n)
          oacc[m][n] = __builtin_amdgcn_mfma_f32_16x16x32_bf16(pa[m], vb[n], oacc[m][n], 0, 0, 0);
    }
    __syncthreads();   // barrier2: all PV reads of Vts / softmax reads of Mw done

    // ---- finish stage(t+1): V perm -> Vts, mask -> Mw ----
    {
      union { unsigned u[4]; s16x8 v; } lo, hi;
#pragma unroll
      for (int j = 0; j < 4; ++j) {
        lo.u[j] = __builtin_amdgcn_perm(w[2 * j + 1], w[2 * j], 0x05040100u);
        hi.u[j] = __builtin_amdgcn_perm(w[2 * j + 1], w[2 * j], 0x07060302u);
      }
      int d0 = dp * 2, swv = (dp & 7) << 4;
      *(s16x8*)(Vts + d0 * 128 + ((g * 16) ^ swv)) = lo.v;
      *(s16x8*)(Vts + (d0 + 1) * 128 + ((g * 16) ^ swv)) = hi.v;
      Mw[qrm * 2 + wmi] = mreg;
    }
  }

  // ---- denominator redistribution: reduce over lg (xor 16,32), park in Ls, read per-row ----
#pragma unroll
  for (int qi = 0; qi < 2; ++qi) {
    float v = lsum[qi];
    v += __shfl_xor(v, 16);
    v += __shfl_xor(v, 32);
    if (lg == 0) Ls[wid * 32 + qi * 16 + l15] = v;
  }
  asm volatile("" ::: "memory");   // intra-wave LDS write->read ordering (compiler fence)

  // ---- epilogue: divide by denominator, write bf16 attention output ----
#pragma unroll
  for (int m = 0; m < 2; ++m)
#pragma unroll
    for (int q = 0; q < 4; ++q) {
      int rloc = wid * 32 + m * 16 + lg * 4 + q;
      float inv = 1.0f / Ls[rloc];
      int rg = qt * 128 + rloc;
#pragma unroll
      for (int n = 0; n < 4; ++n)
        Og[(rowbase + rg) * Cn + cbase + n * 16 + l15] = f2bf(oacc[m][n][q] * inv);
    }
}

// ---------- host ----------
extern "C" void kernel_launch(void* const* d_in, const int* in_sizes, int n_in,
                              void* d_out, int out_size, void* d_ws, size_t ws_size,
                              hipStream_t stream) {
  (void)in_sizes; (void)n_in; (void)out_size; (void)ws_size;
  const float* query = (const float*)d_in[0];
  const float* key_  = (const float*)d_in[1];
  const float* value = (const float*)d_in[2];
  const int*   mask  = (const int*)d_in[3];
  const float* Wq = (const float*)d_in[4];
  const float* Wk = (const float*)d_in[5];
  const float* Wv = (const float*)d_in[6];
  const float* Wp = (const float*)d_in[7];
  const float* bp = (const float*)d_in[8];

  char* ws = (char*)d_ws;
  const size_t SX = (size_t)Mn * Cn * 2;   // 16 MiB
  const size_t SW = (size_t)Cn * Cn * 2;   // 2 MiB
  unsigned short* Xq  = (unsigned short*)(ws);
  unsigned short* Xk  = (unsigned short*)(ws + SX);
  unsigned short* Xv  = (unsigned short*)(ws + 2 * SX);
  unsigned short* Wqb = (unsigned short*)(ws + 3 * SX);
  unsigned short* Wkb = (unsigned short*)(ws + 3 * SX + SW);
  unsigned short* Wvb = (unsigned short*)(ws + 3 * SX + 2 * SW);
  unsigned short* Wpb = (unsigned short*)(ws + 3 * SX + 3 * SW);
  unsigned short* Qb  = (unsigned short*)(ws + 3 * SX + 4 * SW);
  unsigned short* Kb  = (unsigned short*)(ws + 4 * SX + 4 * SW);
  unsigned short* Vb  = (unsigned short*)(ws + 5 * SX + 4 * SW);
  unsigned*       mb  = (unsigned*)(ws + 6 * SX + 4 * SW);
  unsigned short* AO  = Xq;  // alias: Xq dead after QKV GEMM launch

  const int NPREP = 3 * ((Mn * Cn / 4) / 256) + 4 * ((Cn * Cn / 4) / 256)
                    + (Tn * Tn) / 256;   // 24576 + 4096 + 16384 = 45056
  k_prep<<<dim3(NPREP), dim3(256), 0, stream>>>(query, key_, value, Wq, Wk, Wv, Wp, mask,
                                                Xq, Xk, Xv, Wqb, Wkb, Wvb, Wpb, mb);

  k_gemmQKV<<<dim3(8, 64, 3), dim3(256), 0, stream>>>(Xq, Xk, Xv, Wqb, Wkb, Wvb,
                                                      Qb, Kb, Vb);

  k_attn<<<dim3(16, 64), dim3(256), 0, stream>>>(Qb, Kb, Vb, mb, AO);

  k_gemmO<<<dim3(8, 64), dim3(256), 0, stream>>>(AO, Wpb, (float*)d_out, bp);
}